// Round 1
// baseline (1345.247 us; speedup 1.0000x reference)
//
#include <hip/hip_runtime.h>
#include <stdint.h>

// Problem constants (reference shapes are fixed: outputs [8,16,384,384] fp32)
#define B_ 8
#define D_ 16
#define H_ 384
#define W_ 384
constexpr int HW   = H_ * W_;     // 147456
constexpr int DHW  = D_ * HW;     // 2359296
constexpr int NTOT = B_ * DHW;    // 18874368
constexpr int NCOL = B_ * HW;     // 1179648
constexpr unsigned INF = 0xFFFFFFFFu;

constexpr float T_LOW  = 0.8f;
constexpr float T_HIGH = 0.92f;
constexpr unsigned DUST_MIN = 20u;

// ---------------- lock-free union-find ----------------
// Parent pointers only ever decrease (atomicMin linking), so find() terminates
// even with stale cross-XCD reads; the unite retry loop re-links using the
// authoritative value returned by atomicMin.
__device__ __forceinline__ unsigned uf_find(const unsigned* __restrict__ L, unsigned x) {
    unsigned p = L[x];
    while (p != x) { x = p; p = L[x]; }
    return x;
}

__device__ __forceinline__ void uf_union(unsigned* L, unsigned a, unsigned b) {
    while (true) {
        a = uf_find(L, a);
        b = uf_find(L, b);
        if (a == b) return;
        unsigned lo = a < b ? a : b;
        unsigned hi = a < b ? b : a;
        unsigned old = atomicMin(&L[hi], lo);
        if (old == hi) return;   // hi was a true root, now linked to lo
        a = lo; b = old;         // hi already had parent `old`; merge lo with old
    }
}

// ---------------- kernels ----------------

// CCL1 init: label = self-index where weak, else INF
__global__ void k_init1(const float* __restrict__ x, unsigned* __restrict__ L) {
    int i = blockIdx.x * blockDim.x + threadIdx.x;
    if (i >= NTOT) return;
    L[i] = (x[i] >= T_LOW) ? (unsigned)i : INF;
}

// one-pass merge of forward 6-connectivity edges (+w, +h, +z), per batch
__global__ void k_merge(unsigned* L) {
    int i = blockIdx.x * blockDim.x + threadIdx.x;
    if (i >= NTOT) return;
    if (L[i] == INF) return;
    int w = i % W_;
    int h = (i / W_) % H_;
    int z = (i / HW) % D_;
    if (w < W_ - 1 && L[i + 1]  != INF) uf_union(L, i, i + 1);
    if (h < H_ - 1 && L[i + W_] != INF) uf_union(L, i, i + W_);
    if (z < D_ - 1 && L[i + HW] != INF) uf_union(L, i, i + HW);
}

// flatten labels to roots; mark roots whose component contains a strong voxel
__global__ void k_flatten_flag(const float* __restrict__ x, unsigned* L,
                               unsigned* __restrict__ flag) {
    int i = blockIdx.x * blockDim.x + threadIdx.x;
    if (i >= NTOT) return;
    if (L[i] == INF) return;
    unsigned r = uf_find(L, i);
    L[i] = r;
    if (x[i] >= T_HIGH) flag[r] = 1u;   // racing same-value stores are fine
}

// hysteresis result per column (16-bit z mask) + anisotropic closing along z
__global__ void k_close(const unsigned* __restrict__ L, const unsigned* __restrict__ flag,
                        unsigned short* __restrict__ colmask) {
    int c = blockIdx.x * blockDim.x + threadIdx.x;
    if (c >= NCOL) return;
    int b   = c / HW;
    int rem = c - b * HW;
    int base = b * DHW + rem;
    unsigned m = 0u;
    for (int z = 0; z < D_; ++z) {
        unsigned l = L[base + z * HW];
        if (l != INF && flag[l]) m |= (1u << z);
    }
    // dilation: OOB = background (shift-in zeros)
    unsigned dil = (m | (m << 1) | (m >> 1)) & 0xFFFFu;
    // erosion: OOB = foreground (force edge bits to 1)
    unsigned ero = dil & ((dil << 1) | 1u) & ((dil >> 1) | 0x8000u);
    colmask[c] = (unsigned short)ero;
}

// CCL2 init from packed closed mask
__global__ void k_init2(const unsigned short* __restrict__ colmask, unsigned* __restrict__ L) {
    int c = blockIdx.x * blockDim.x + threadIdx.x;
    if (c >= NCOL) return;
    int b   = c / HW;
    int rem = c - b * HW;
    int base = b * DHW + rem;
    unsigned m = colmask[c];
    for (int z = 0; z < D_; ++z) {
        int i = base + z * HW;
        L[i] = ((m >> z) & 1u) ? (unsigned)i : INF;
    }
}

// flatten + per-component voxel count
__global__ void k_flatten_count(unsigned* L, unsigned* __restrict__ cnt) {
    int i = blockIdx.x * blockDim.x + threadIdx.x;
    if (i >= NTOT) return;
    if (L[i] == INF) return;
    unsigned r = uf_find(L, i);
    L[i] = r;
    atomicAdd(&cnt[r], 1u);
}

// final: keep components with size >= DUST_MIN, write 0/1 float
__global__ void k_out(const unsigned* __restrict__ L, const unsigned* __restrict__ cnt,
                      float* __restrict__ out) {
    int i = blockIdx.x * blockDim.x + threadIdx.x;
    if (i >= NTOT) return;
    unsigned l = L[i];
    float v = 0.0f;
    if (l != INF && cnt[l] >= DUST_MIN) v = 1.0f;
    out[i] = v;
}

extern "C" void kernel_launch(void* const* d_in, const int* in_sizes, int n_in,
                              void* d_out, int out_size, void* d_ws, size_t ws_size,
                              hipStream_t stream) {
    const float* x = (const float*)d_in[0];
    float* out = (float*)d_out;

    // workspace layout: labels [NTOT u32] | aux (flags/counts) [NTOT u32] | colmask [NCOL u16]
    const size_t needed = (size_t)NTOT * 8 + (size_t)NCOL * 2;
    if (ws_size < needed) return;  // fail loudly via wrong output
    char* ws = (char*)d_ws;
    unsigned* L   = (unsigned*)ws;
    unsigned* aux = (unsigned*)(ws + (size_t)NTOT * 4);
    unsigned short* colmask = (unsigned short*)(ws + (size_t)NTOT * 8);

    dim3 blk(256);
    dim3 grdN((NTOT + 255) / 256);
    dim3 grdC((NCOL + 255) / 256);

    // ---- CCL #1 on weak mask + strong-flag hysteresis ----
    hipMemsetAsync(aux, 0, (size_t)NTOT * 4, stream);
    k_init1<<<grdN, blk, 0, stream>>>(x, L);
    k_merge<<<grdN, blk, 0, stream>>>(L);
    k_flatten_flag<<<grdN, blk, 0, stream>>>(x, L, aux);

    // ---- hysteresis mask + z-closing, packed per column ----
    k_close<<<grdC, blk, 0, stream>>>(L, aux, colmask);

    // ---- CCL #2 on closed mask + size filter ----
    hipMemsetAsync(aux, 0, (size_t)NTOT * 4, stream);
    k_init2<<<grdC, blk, 0, stream>>>(colmask, L);
    k_merge<<<grdN, blk, 0, stream>>>(L);
    k_flatten_count<<<grdN, blk, 0, stream>>>(L, aux);
    k_out<<<grdN, blk, 0, stream>>>(L, aux, out);
}

// Round 2
// 681.928 us; speedup vs baseline: 1.9727x; 1.9727x over previous
//
#include <hip/hip_runtime.h>
#include <stdint.h>

// Fixed problem shape: outputs [8,16,384,384] fp32
#define B_ 8
#define D_ 16
#define H_ 384
#define W_ 384
constexpr int HW   = H_ * W_;     // 147456
constexpr int DHW  = D_ * HW;     // 2359296
constexpr int NTOT = B_ * DHW;    // 18874368
constexpr int NCOL = B_ * HW;     // 1179648
constexpr unsigned INF = 0xFFFFFFFFu;

constexpr float T_LOW  = 0.8f;
constexpr float T_HIGH = 0.92f;
constexpr unsigned DUST_MIN = 20u;

// ---- tiling for local CCL: full z, 8 x 32 in h,w -> 4096 voxels, 16 KB LDS ----
constexpr int TZ = 16, TH = 8, TW = 32;
constexpr int TILE = TZ * TH * TW;        // 4096
constexpr int THB = H_ / TH;              // 48
constexpr int TWB = W_ / TW;              // 12
constexpr int TILES_PER_B = THB * TWB;    // 576
constexpr int NTILES = B_ * TILES_PER_B;  // 4608

// ---- boundary-edge enumeration (only w-faces and h-faces; z fully in-tile) ----
constexpr int NWPOS = TWB - 1;                 // 11 w-face positions
constexpr int NHPOS = THB - 1;                 // 47 h-face positions
constexpr int WE_PER_B = D_ * H_ * NWPOS;      // 67584
constexpr int HE_PER_B = D_ * NHPOS * W_;      // 288768
constexpr int E_PER_B  = WE_PER_B + HE_PER_B;  // 356352
constexpr int NEDGES   = B_ * E_PER_B;         // 2850816

// ---------------- global union-find (lock-free, monotone-decreasing parents) ----
__device__ __forceinline__ unsigned uf_find(const unsigned* L, unsigned x) {
    unsigned p = L[x];
    while (p != x) { x = p; p = L[x]; }
    return x;
}

__device__ __forceinline__ void uf_union(unsigned* L, unsigned a, unsigned b) {
    while (true) {
        a = uf_find(L, a);
        b = uf_find(L, b);
        if (a == b) return;
        unsigned lo = a < b ? a : b;
        unsigned hi = a < b ? b : a;
        unsigned old = atomicMin(&L[hi], lo);
        if (old == hi) return;
        a = lo; b = old;
    }
}

// ---------------- LDS union-find ----------------
__device__ __forceinline__ unsigned luf_find(volatile unsigned* sl, unsigned x) {
    unsigned p = sl[x];
    while (p != x) { x = p; p = sl[x]; }
    return x;
}

__device__ __forceinline__ void luf_union(unsigned* sl, unsigned a, unsigned b) {
    while (true) {
        a = luf_find(sl, a);
        b = luf_find(sl, b);
        if (a == b) return;
        unsigned lo = a < b ? a : b;
        unsigned hi = a < b ? b : a;
        unsigned old = atomicMin(&sl[hi], lo);
        if (old == hi) return;
        a = lo; b = old;
    }
}

// ---------------- kernels ----------------

// Local CCL on the weak mask; also emits per-column strong-bit mask.
// Thread t owns one (h,w) column across all 16 z-slices.
__global__ void k_local1(const float* __restrict__ x, unsigned* __restrict__ L,
                         unsigned short* __restrict__ strongmask) {
    __shared__ unsigned sl[TILE];
    int tile = blockIdx.x;
    int b  = tile / TILES_PER_B;
    int tr = tile % TILES_PER_B;
    int h0 = (tr / TWB) * TH;
    int w0 = (tr % TWB) * TW;
    int t  = threadIdx.x;            // 0..255
    int lh = t >> 5, lw = t & 31;
    int p_g    = (h0 + lh) * W_ + (w0 + lw);   // in-slice offset
    int base_g = b * DHW + p_g;

    unsigned weakbits = 0, strongbits = 0;
    #pragma unroll
    for (int z = 0; z < TZ; ++z) {
        float v = x[base_g + z * HW];
        unsigned wk = (v >= T_LOW) ? 1u : 0u;
        weakbits   |= wk << z;
        strongbits |= ((v >= T_HIGH) ? 1u : 0u) << z;
        sl[z * 256 + t] = wk ? (unsigned)(z * 256 + t) : INF;
    }
    strongmask[b * HW + p_g] = (unsigned short)strongbits;
    __syncthreads();

    #pragma unroll
    for (int z = 0; z < TZ; ++z) {
        if (!((weakbits >> z) & 1)) continue;
        int lv = z * 256 + t;
        if (lw < TW - 1 && sl[lv + 1]   != INF) luf_union(sl, lv, lv + 1);
        if (lh < TH - 1 && sl[lv + 32]  != INF) luf_union(sl, lv, lv + 32);
        if (z  < TZ - 1 && sl[lv + 256] != INF) luf_union(sl, lv, lv + 256);
    }
    __syncthreads();

    #pragma unroll
    for (int z = 0; z < TZ; ++z) {
        unsigned out = INF;
        if ((weakbits >> z) & 1) {
            unsigned r = luf_find(sl, z * 256 + t);
            out = (unsigned)(b * DHW + (r >> 8) * HW
                             + (h0 + ((r >> 5) & 7)) * W_ + (w0 + (r & 31)));
        }
        L[base_g + z * HW] = out;
    }
}

// Local CCL on the closed mask (read from packed column masks).
__global__ void k_local2(const unsigned short* __restrict__ colmask,
                         unsigned* __restrict__ L) {
    __shared__ unsigned sl[TILE];
    int tile = blockIdx.x;
    int b  = tile / TILES_PER_B;
    int tr = tile % TILES_PER_B;
    int h0 = (tr / TWB) * TH;
    int w0 = (tr % TWB) * TW;
    int t  = threadIdx.x;
    int lh = t >> 5, lw = t & 31;
    int p_g    = (h0 + lh) * W_ + (w0 + lw);
    int base_g = b * DHW + p_g;

    unsigned fgbits = colmask[b * HW + p_g];
    #pragma unroll
    for (int z = 0; z < TZ; ++z)
        sl[z * 256 + t] = ((fgbits >> z) & 1) ? (unsigned)(z * 256 + t) : INF;
    __syncthreads();

    #pragma unroll
    for (int z = 0; z < TZ; ++z) {
        if (!((fgbits >> z) & 1)) continue;
        int lv = z * 256 + t;
        if (lw < TW - 1 && sl[lv + 1]   != INF) luf_union(sl, lv, lv + 1);
        if (lh < TH - 1 && sl[lv + 32]  != INF) luf_union(sl, lv, lv + 32);
        if (z  < TZ - 1 && sl[lv + 256] != INF) luf_union(sl, lv, lv + 256);
    }
    __syncthreads();

    #pragma unroll
    for (int z = 0; z < TZ; ++z) {
        unsigned out = INF;
        if ((fgbits >> z) & 1) {
            unsigned r = luf_find(sl, z * 256 + t);
            out = (unsigned)(b * DHW + (r >> 8) * HW
                             + (h0 + ((r >> 5) & 7)) * W_ + (w0 + (r & 31)));
        }
        L[base_g + z * HW] = out;
    }
}

// Merge across tile faces only (w-faces and h-faces).
__global__ void k_edges(unsigned* L) {
    int e = blockIdx.x * blockDim.x + threadIdx.x;
    if (e >= NEDGES) return;
    int b = e / E_PER_B;
    int r = e % E_PER_B;
    int i, j;
    if (r < WE_PER_B) {
        int z   = r / (H_ * NWPOS);
        int rem = r % (H_ * NWPOS);
        int h   = rem / NWPOS;
        int wi  = rem % NWPOS;
        int w   = wi * TW + (TW - 1);
        i = b * DHW + z * HW + h * W_ + w;
        j = i + 1;
    } else {
        r -= WE_PER_B;
        int z   = r / (NHPOS * W_);
        int rem = r % (NHPOS * W_);
        int hi  = rem / W_;
        int w   = rem % W_;
        int h   = hi * TH + (TH - 1);
        i = b * DHW + z * HW + h * W_ + w;
        j = i + W_;
    }
    unsigned li = L[i], lj = L[j];
    if (li == INF || lj == INF) return;
    uf_union(L, li, lj);
}

// Flatten labels; flag roots whose component has a strong voxel.
__global__ void k_flatten_flag(const unsigned short* __restrict__ strongmask,
                               unsigned* L, unsigned* __restrict__ flag) {
    int i = blockIdx.x * blockDim.x + threadIdx.x;
    if (i >= NTOT) return;
    unsigned l = L[i];
    if (l == INF) return;
    unsigned r = uf_find(L, l);
    L[i] = r;
    int rem = i % DHW;
    int z   = rem / HW;
    int c   = (i / DHW) * HW + (rem % HW);
    if ((strongmask[c] >> z) & 1) flag[r] = 1u;
}

// Hysteresis mask per column + z-closing; emits packed closed mask.
__global__ void k_close(const unsigned* __restrict__ L, const unsigned* __restrict__ flag,
                        unsigned short* __restrict__ colmask) {
    int c = blockIdx.x * blockDim.x + threadIdx.x;
    if (c >= NCOL) return;
    int b = c / HW;
    int p = c % HW;
    int base = b * DHW + p;
    unsigned m = 0u;
    #pragma unroll
    for (int z = 0; z < D_; ++z) {
        unsigned l = L[base + z * HW];
        if (l != INF && flag[l]) m |= (1u << z);
    }
    unsigned dil = (m | (m << 1) | (m >> 1)) & 0xFFFFu;
    unsigned ero = dil & ((dil << 1) | 1u) & ((dil >> 1) | 0x8000u);
    colmask[c] = (unsigned short)ero;
}

// Flatten + per-component voxel count.
__global__ void k_flatten_count(unsigned* L, unsigned* __restrict__ cnt) {
    int i = blockIdx.x * blockDim.x + threadIdx.x;
    if (i >= NTOT) return;
    unsigned l = L[i];
    if (l == INF) return;
    unsigned r = uf_find(L, l);
    L[i] = r;
    atomicAdd(&cnt[r], 1u);
}

// Keep components with size >= DUST_MIN, write 0/1 float.
__global__ void k_out(const unsigned* __restrict__ L, const unsigned* __restrict__ cnt,
                      float* __restrict__ out) {
    int i = blockIdx.x * blockDim.x + threadIdx.x;
    if (i >= NTOT) return;
    unsigned l = L[i];
    out[i] = (l != INF && cnt[l] >= DUST_MIN) ? 1.0f : 0.0f;
}

extern "C" void kernel_launch(void* const* d_in, const int* in_sizes, int n_in,
                              void* d_out, int out_size, void* d_ws, size_t ws_size,
                              hipStream_t stream) {
    const float* x = (const float*)d_in[0];
    float* out = (float*)d_out;

    // workspace: L [NTOT u32] | aux (flags/counts) [NTOT u32] | masks [NCOL u16]
    // (strongmask and colmask alias: lifetimes don't overlap)
    const size_t needed = (size_t)NTOT * 8 + (size_t)NCOL * 2;
    if (ws_size < needed) return;
    char* ws = (char*)d_ws;
    unsigned* L   = (unsigned*)ws;
    unsigned* aux = (unsigned*)(ws + (size_t)NTOT * 4);
    unsigned short* masks = (unsigned short*)(ws + (size_t)NTOT * 8);

    dim3 blk(256);
    dim3 grdN((NTOT + 255) / 256);
    dim3 grdC((NCOL + 255) / 256);
    dim3 grdT(NTILES);
    dim3 grdE((NEDGES + 255) / 256);

    // ---- CCL #1 (weak mask) + hysteresis ----
    hipMemsetAsync(aux, 0, (size_t)NTOT * 4, stream);
    k_local1<<<grdT, blk, 0, stream>>>(x, L, masks);
    k_edges<<<grdE, blk, 0, stream>>>(L);
    k_flatten_flag<<<grdN, blk, 0, stream>>>(masks, L, aux);

    // ---- hysteresis + z-closing -> packed column mask ----
    k_close<<<grdC, blk, 0, stream>>>(L, aux, masks);

    // ---- CCL #2 (closed mask) + dust removal ----
    hipMemsetAsync(aux, 0, (size_t)NTOT * 4, stream);
    k_local2<<<grdT, blk, 0, stream>>>(masks, L);
    k_edges<<<grdE, blk, 0, stream>>>(L);
    k_flatten_count<<<grdN, blk, 0, stream>>>(L, aux);
    k_out<<<grdN, blk, 0, stream>>>(L, aux, out);
}